// Round 16
// baseline (407.496 us; speedup 1.0000x reference)
//
#include <hip/hip_runtime.h>
#include <hip/hip_fp16.h>
#include <math.h>

#define NN 50000          // nodes
#define NE 800000         // edges (without self loops)
#define NT 850000         // edges + self loops
#define NB 256            // batch graphs
#define FIN 128           // input feature dim
#define HC 256            // H*C
#define NH 4              // heads
#define CD 64             // channels per head
#define NEG 0.2f
#define SCAN_B 196        // ceil(NN/256)
#define PSPL 8            // pool split factor

typedef _Float16 half8 __attribute__((ext_vector_type(8)));
typedef float f32x4 __attribute__((ext_vector_type(4)));

__device__ __forceinline__ void gld16(const void* g, void* l) {
    __builtin_amdgcn_global_load_lds(
        (const __attribute__((address_space(1))) void*)g,
        (__attribute__((address_space(3))) void*)l, 16, 0, 0);
}

// ---------------- init: zero cnt, batch bounds (no cross-block comm) ----------------

__global__ __launch_bounds__(256) void init_kernel(const int* __restrict__ batch,
        int* __restrict__ cnt, int* __restrict__ bstart) {
    int i = blockIdx.x * 256 + threadIdx.x;
    if (i >= NN) return;
    cnt[i] = 0;
    int b = batch[i];
    if (i == 0) {
        for (int bb = 0; bb <= b; ++bb) bstart[bb] = 0;
    } else {
        int pb = batch[i - 1];
        if (pb != b) for (int bb = pb + 1; bb <= b; ++bb) bstart[bb] = i;
    }
    if (i == NN - 1) {
        for (int bb = b + 1; bb <= NB; ++bb) bstart[bb] = NN;
    }
}

__global__ void hist_kernel(const int* __restrict__ ei, int* __restrict__ cnt) {
    int e = blockIdx.x * blockDim.x + threadIdx.x;
    if (e < NE) {
        atomicAdd(&cnt[ei[NE + e]], 1);         // dst row of edge_index
    } else if (e < NT) {
        atomicAdd(&cnt[e - NE], 1);             // self loop
    }
}

__global__ __launch_bounds__(256) void part_kernel(const int* __restrict__ cnt,
                                                   int* __restrict__ part) {
    __shared__ int red[4];
    int i = blockIdx.x * 256 + threadIdx.x;
    int v = (i < NN) ? cnt[i] : 0;
#pragma unroll
    for (int off = 32; off > 0; off >>= 1) v += __shfl_down(v, off);
    if ((threadIdx.x & 63) == 0) red[threadIdx.x >> 6] = v;
    __syncthreads();
    if (threadIdx.x == 0) part[blockIdx.x] = red[0] + red[1] + red[2] + red[3];
}

__global__ __launch_bounds__(256) void offs_kernel(const int* __restrict__ part,
                                                   int* __restrict__ boff) {
    __shared__ int sh[256];
    int t = threadIdx.x;
    sh[t] = (t < SCAN_B) ? part[t] : 0;
    __syncthreads();
    for (int off = 1; off < 256; off <<= 1) {
        int add = (t >= off) ? sh[t - off] : 0;
        __syncthreads();
        sh[t] += add;
        __syncthreads();
    }
    boff[t] = (t == 0) ? 0 : sh[t - 1];   // exclusive block offsets
}

__global__ __launch_bounds__(256) void write_scan_kernel(const int* __restrict__ cnt,
        const int* __restrict__ boff, int* __restrict__ rowptr, int* __restrict__ cursor) {
    __shared__ int sh[256];
    int t = threadIdx.x;
    int i = blockIdx.x * 256 + t;
    int v = (i < NN) ? cnt[i] : 0;
    sh[t] = v;
    __syncthreads();
    for (int off = 1; off < 256; off <<= 1) {
        int add = (t >= off) ? sh[t - off] : 0;
        __syncthreads();
        sh[t] += add;
        __syncthreads();
    }
    int run = boff[blockIdx.x] + sh[t] - v;   // exclusive prefix
    if (i < NN) { rowptr[i] = run; cursor[i] = run; }
    if (i == NN - 1) rowptr[NN] = run + v;
}

__global__ void scatter_kernel(const int* __restrict__ ei, int* __restrict__ cursor,
                               int* __restrict__ colsrc) {
    int e = blockIdx.x * blockDim.x + threadIdx.x;
    int s, d;
    if (e < NE)      { s = ei[e]; d = ei[NE + e]; }
    else if (e < NT) { s = e - NE; d = s; }
    else return;
    int pos = atomicAdd(&cursor[d], 1);
    colsrc[pos] = s;
}

// ---------------- W prep: all 3 layers' hi-images in ONE dispatch ----------------
//   WtS[(kchunk*256 + col)*8 + e] = fp16(W[kchunk*8 + e][col])
// blocks 0..15 -> W1 (K=128), 16..47 -> W2 (K=256), 48..79 -> W3 (K=256)

__global__ __launch_bounds__(256) void wprep_all_kernel(
        const float* __restrict__ W1, const float* __restrict__ W2,
        const float* __restrict__ W3,
        _Float16* __restrict__ WtS1, _Float16* __restrict__ WtS2,
        _Float16* __restrict__ WtS3) {
    __shared__ float sm[8][257];
    const int t = threadIdx.x;
    int b = blockIdx.x;
    const float* W;
    _Float16* O;
    int lb;
    if (b < 16)      { W = W1; O = WtS1; lb = b; }
    else if (b < 48) { W = W2; O = WtS2; lb = b - 16; }
    else             { W = W3; O = WtS3; lb = b - 48; }
    const int kb = lb * 8;
#pragma unroll
    for (int i = 0; i < 8; ++i) {
        int idx = i * 256 + t;
        sm[idx >> 8][idx & 255] = W[(size_t)(kb + (idx >> 8)) * HC + (idx & 255)];
    }
    __syncthreads();
    half8 o;
#pragma unroll
    for (int r = 0; r < 8; ++r) o[r] = (_Float16)sm[r][t];
    *reinterpret_cast<half8*>(&O[((size_t)lb * 256 + t) * 8]) = o;
}

// ---- MFMA GEMM: 64(M)x128(N) tile, BK=32, 4-buffer DEPTH-3 counted-vmcnt ----
// SINGLE-PASS hi-only: C = fp16(A) @ fp16(W) with fp32 accum (verified
// absmax 4.9e-4 — error budget dominated by fp16 h storage).
// 48 KB LDS -> 3 blocks/CU. Per step:
//   loadA(s+3)->reg, issueB(s+3); MFMA(s); ds_write A(s+1);
//   vmcnt(6|8) + lgkmcnt(0); s_barrier   (2 newest batches in flight, T4)
// grid = 2 * ceil(NN/64): blockIdx.x&1 selects the 128-col half.
// F32IN: layer-1 A read from fp32 x, converted at ds_write.
// Epilogue fuses alpha: each (col-half, wave) owns ONE head's 64 channels.

template<int K, bool F32IN>
__global__ __launch_bounds__(256) void mfma_gemm_kernel(
        const _Float16* __restrict__ Xh, const float* __restrict__ Xf,
        const _Float16* __restrict__ WtS, __half* __restrict__ XHo,
        const float* __restrict__ as_g, const float* __restrict__ ad_g,
        float* __restrict__ aS, float* __restrict__ aD) {
    constexpr int NSTEP = K / 32;            // 4 (K=128) / 8 (K=256)
    __shared__ __align__(16) _Float16 As[4][64 * 32];    // 4 x 4 KB
    __shared__ __align__(16) _Float16 Bs[4][32 * 128];   // 4 x 8 KB (48 KB total)
    const int t = threadIdx.x;
    const int lane = t & 63;
    const int wid = t >> 6;                  // 0..3
    const int wm = wid & 1, wn = wid >> 1;   // 2 row-groups x 2 col-groups(64)
    const int cbb = blockIdx.x & 1;          // column half (0/1)
    const int r0 = (blockIdx.x >> 1) * 64;
    const int cb0 = cbb * 128;
    const int l15 = lane & 15;
    const int kcl = lane >> 4;               // 0..3
    const int srowA = t >> 2;                // 0..63
    const int skcA  = t & 3;                 // 0..3
    const int arow = min(r0 + srowA, NN - 1);

    f32x4 acc[2][4];
#pragma unroll
    for (int i = 0; i < 2; ++i)
#pragma unroll
        for (int j = 0; j < 4; ++j) acc[i][j] = (f32x4)0.f;

    float4 rA[3][2];                         // reg slots, batch % 3

    auto loadA = [&](int s, float4& v0, float4& v1) {
        const int cbase = s * 32;
        if constexpr (F32IN) {
            const float* p = Xf + (size_t)arow * K + cbase + skcA * 8;
            v0 = *reinterpret_cast<const float4*>(p);
            v1 = *reinterpret_cast<const float4*>(p + 4);
        } else {
            v0 = *reinterpret_cast<const float4*>(Xh + (size_t)arow * K + cbase + skcA * 8);
        }
    };
    auto writeA = [&](int buf, float4 v0, float4 v1) {
        _Float16* d = &As[buf][(skcA * 64 + (srowA ^ skcA)) * 8];
        if constexpr (F32IN) {
            float f[8];
            *reinterpret_cast<float4*>(f) = v0;
            *reinterpret_cast<float4*>(f + 4) = v1;
            half8 h;
#pragma unroll
            for (int e = 0; e < 8; ++e) h[e] = (_Float16)f[e];
            *reinterpret_cast<half8*>(d) = h;
        } else {
            *reinterpret_cast<float4*>(d) = v0;
        }
    };
    auto issueB = [&](int s, int buf) {
        const int kbase = s * 4;
#pragma unroll
        for (int r2 = 0; r2 < 2; ++r2) {
            int kc = r2 * 2 + (t >> 7);      // 0..3, wave-uniform
            int col = t & 127;
            gld16(WtS + ((size_t)(kbase + kc) * 256 + cb0 + col) * 8,
                  &Bs[buf][(kc * 128 + col) * 8]);
        }
    };
    auto mfma_step = [&](int buf) {
        half8 a0 = *reinterpret_cast<const half8*>(
            &As[buf][(kcl * 64 + ((wm * 32      + l15) ^ kcl)) * 8]);
        half8 a1 = *reinterpret_cast<const half8*>(
            &As[buf][(kcl * 64 + ((wm * 32 + 16 + l15) ^ kcl)) * 8]);
        const _Float16* bp = &Bs[buf][(kcl * 128 + wn * 64 + l15) * 8];
        __builtin_amdgcn_s_setprio(1);
#pragma unroll
        for (int nf = 0; nf < 4; ++nf) {
            half8 b = *reinterpret_cast<const half8*>(bp + nf * 16 * 8);
            acc[0][nf] = __builtin_amdgcn_mfma_f32_16x16x32_f16(a0, b, acc[0][nf], 0, 0, 0);
            acc[1][nf] = __builtin_amdgcn_mfma_f32_16x16x32_f16(a1, b, acc[1][nf], 0, 0, 0);
        }
        __builtin_amdgcn_s_setprio(0);
    };
    auto wait_steady = [&]() {
        if constexpr (F32IN) asm volatile("s_waitcnt vmcnt(8) lgkmcnt(0)" ::: "memory");
        else                 asm volatile("s_waitcnt vmcnt(6) lgkmcnt(0)" ::: "memory");
        __builtin_amdgcn_s_barrier();
        __builtin_amdgcn_sched_barrier(0);
    };

    // prologue: 3 batches in flight, A0 written, batch 0 complete
    loadA(0, rA[0][0], rA[0][1]); issueB(0, 0);
    loadA(1, rA[1][0], rA[1][1]); issueB(1, 1);
    loadA(2, rA[2][0], rA[2][1]); issueB(2, 2);
    writeA(0, rA[0][0], rA[0][1]);
    wait_steady();

#pragma unroll
    for (int s = 0; s < NSTEP - 3; ++s) {
        loadA(s + 3, rA[(s + 3) % 3][0], rA[(s + 3) % 3][1]);
        issueB(s + 3, (s + 3) & 3);
        mfma_step(s & 3);
        writeA((s + 1) & 3, rA[(s + 1) % 3][0], rA[(s + 1) % 3][1]);
        wait_steady();
    }
    // tail: s = NSTEP-3, NSTEP-2, NSTEP-1
    mfma_step((NSTEP - 3) & 3);
    writeA((NSTEP - 2) & 3, rA[(NSTEP - 2) % 3][0], rA[(NSTEP - 2) % 3][1]);
    if constexpr (F32IN) asm volatile("s_waitcnt vmcnt(4) lgkmcnt(0)" ::: "memory");
    else                 asm volatile("s_waitcnt vmcnt(3) lgkmcnt(0)" ::: "memory");
    __builtin_amdgcn_s_barrier();
    __builtin_amdgcn_sched_barrier(0);
    mfma_step((NSTEP - 2) & 3);
    writeA((NSTEP - 1) & 3, rA[(NSTEP - 1) % 3][0], rA[(NSTEP - 1) % 3][1]);
    asm volatile("s_waitcnt vmcnt(0) lgkmcnt(0)" ::: "memory");
    __builtin_amdgcn_s_barrier();
    __builtin_amdgcn_sched_barrier(0);
    mfma_step((NSTEP - 1) & 3);

    // ---------------- epilogue: XH stores + fused alpha (one head/wave) ------
    const int rb = r0 + wm * 32 + (lane >> 4) * 4;
    const int cbg = cb0 + wn * 64 + l15;     // global column of frag lane
    const int head = cbb * 2 + wn;
    float asv[4], adv[4];
#pragma unroll
    for (int nf = 0; nf < 4; ++nf) {
        asv[nf] = as_g[cbg + nf * 16];
        adv[nf] = ad_g[cbg + nf * 16];
    }
#pragma unroll
    for (int mf = 0; mf < 2; ++mf)
#pragma unroll
        for (int r = 0; r < 4; ++r) {
            int row = rb + mf * 16 + r;
            float s0 = 0.f, d0 = 0.f;
#pragma unroll
            for (int nf = 0; nf < 4; ++nf) {
                float a = acc[mf][nf][r];
                s0 += a * asv[nf];
                d0 += a * adv[nf];
            }
#pragma unroll
            for (int off = 1; off < 16; off <<= 1) {
                s0 += __shfl_xor(s0, off);
                d0 += __shfl_xor(d0, off);
            }
            if (row < NN) {
                if (l15 == 0) {
                    aS[row * 4 + head] = s0;
                    aD[row * 4 + head] = d0;
                }
#pragma unroll
                for (int nf = 0; nf < 4; ++nf)
                    XHo[(size_t)row * HC + cbg + nf * 16] = __float2half(acc[mf][nf][r]);
            }
        }
}

// ---- aggregation, single-wave-load variant: lane owns channels 4l..4l+3 ----
// Per edge: ONE dwordx2 per lane (512 B contiguous row per wave instruction,
// half the VMEM instructions of the 2-load variant). Each lane applies its
// head's weight (head = lane>>4), read broadcast from per-wave LDS wbuf.
// Unroll 16 -> same in-flight instruction count as before, 2x bytes in flight.
// logits O(1) -> exp without max-shift == ref softmax.

#define LEAKY(v) ((v) > 0.f ? (v) : NEG * (v))

template<int RELU, int SPLIT>
__global__ __launch_bounds__(256) void aggregate_kernel(
        const int* __restrict__ rowptr, const int* __restrict__ colsrc,
        const float* __restrict__ aS, const float* __restrict__ aD,
        const __half* __restrict__ XH,
        const float* __restrict__ bias, float* __restrict__ OUT,
        __half* __restrict__ OUTh) {
    __shared__ float wbuf[4][64][4];   // [wave][edge][head]  4 KB
    __shared__ int   ibuf[4][64];      // 1 KB
    const int wslot = threadIdx.x >> 6;
    int n = blockIdx.x * 4 + wslot;
    int lane = threadIdx.x & 63;
    const int h = lane >> 4;           // this lane's head
    float4 adv = *reinterpret_cast<const float4*>(aD + n * 4);
    float z = 0.f;
    float a0 = 0.f, a1 = 0.f, a2 = 0.f, a3 = 0.f;
    int jb = rowptr[n], je = rowptr[n + 1];   // deg >= 1 (self loop)
    for (int c0 = jb; c0 < je; c0 += 64) {
        int cnt = min(64, je - c0);
        // phase 1: lane-parallel edge weights into per-wave LDS
        {
            int e = min(c0 + lane, je - 1);
            int s = colsrc[e];
            float4 sv = *reinterpret_cast<const float4*>(aS + s * 4);
            float4 w;
            w.x = __expf(LEAKY(sv.x + adv.x));
            w.y = __expf(LEAKY(sv.y + adv.y));
            w.z = __expf(LEAKY(sv.z + adv.z));
            w.w = __expf(LEAKY(sv.w + adv.w));
            *reinterpret_cast<float4*>(&wbuf[wslot][lane][0]) = w;
            ibuf[wslot][lane] = s;
            // same-wave producer/consumer: lgkmcnt ordering, no barrier needed
        }
        // phase 2: batched single-load gather
        int u = 0;
        for (; u + 16 <= cnt; u += 16) {
            int sidx[16];
            float w[16];
#pragma unroll
            for (int k = 0; k < 16; ++k) {
                sidx[k] = ibuf[wslot][u + k];
                w[k] = wbuf[wslot][u + k][h];
            }
            uint2 hv[16];
#pragma unroll
            for (int k = 0; k < 16; ++k)
                hv[k] = *reinterpret_cast<const uint2*>(XH + (size_t)sidx[k] * HC + lane * 4);
#pragma unroll
            for (int k = 0; k < 16; ++k) {
                float2 f0 = __half22float2(*reinterpret_cast<__half2*>(&hv[k].x));
                float2 f1 = __half22float2(*reinterpret_cast<__half2*>(&hv[k].y));
                a0 += w[k] * f0.x; a1 += w[k] * f0.y;
                a2 += w[k] * f1.x; a3 += w[k] * f1.y;
                z  += w[k];
            }
        }
        for (; u + 4 <= cnt; u += 4) {
            int sidx[4];
            float w[4];
#pragma unroll
            for (int k = 0; k < 4; ++k) {
                sidx[k] = ibuf[wslot][u + k];
                w[k] = wbuf[wslot][u + k][h];
            }
            uint2 hv[4];
#pragma unroll
            for (int k = 0; k < 4; ++k)
                hv[k] = *reinterpret_cast<const uint2*>(XH + (size_t)sidx[k] * HC + lane * 4);
#pragma unroll
            for (int k = 0; k < 4; ++k) {
                float2 f0 = __half22float2(*reinterpret_cast<__half2*>(&hv[k].x));
                float2 f1 = __half22float2(*reinterpret_cast<__half2*>(&hv[k].y));
                a0 += w[k] * f0.x; a1 += w[k] * f0.y;
                a2 += w[k] * f1.x; a3 += w[k] * f1.y;
                z  += w[k];
            }
        }
        for (; u < cnt; ++u) {
            int s0 = ibuf[wslot][u];
            float w0 = wbuf[wslot][u][h];
            uint2 hv = *reinterpret_cast<const uint2*>(XH + (size_t)s0 * HC + lane * 4);
            float2 f0 = __half22float2(*reinterpret_cast<__half2*>(&hv.x));
            float2 f1 = __half22float2(*reinterpret_cast<__half2*>(&hv.y));
            a0 += w0 * f0.x; a1 += w0 * f0.y;
            a2 += w0 * f1.x; a3 += w0 * f1.y;
            z  += w0;
        }
    }
    float iz = 1.f / (z + 1e-16f);
    float4 bv = *reinterpret_cast<const float4*>(bias + lane * 4);
    float o0 = a0 * iz + bv.x;
    float o1 = a1 * iz + bv.y;
    float o2 = a2 * iz + bv.z;
    float o3 = a3 * iz + bv.w;
    if (RELU) {
        o0 = fmaxf(o0, 0.f); o1 = fmaxf(o1, 0.f);
        o2 = fmaxf(o2, 0.f); o3 = fmaxf(o3, 0.f);
    }
    if (SPLIT) {
        __half2 p0(__float2half(o0), __float2half(o1));
        __half2 p1(__float2half(o2), __float2half(o3));
        uint2 pk;
        pk.x = *reinterpret_cast<unsigned int*>(&p0);
        pk.y = *reinterpret_cast<unsigned int*>(&p1);
        *reinterpret_cast<uint2*>(OUTh + (size_t)n * HC + lane * 4) = pk;
    } else {
        *reinterpret_cast<float4*>(OUT + (size_t)n * HC + lane * 4) =
            make_float4(o0, o1, o2, o3);
    }
}

// ---------------- global max pool (two-stage, deterministic) ----------------

__global__ __launch_bounds__(256) void pool1_kernel(const float* __restrict__ Hf,
        const int* __restrict__ bstart, float* __restrict__ part) {
    int b = blockIdx.x / PSPL, sp = blockIdx.x % PSPL;
    int c = threadIdx.x;
    int i0 = bstart[b], i1 = bstart[b + 1];
    float m = -INFINITY;
    for (int i = i0 + sp; i < i1; i += PSPL) m = fmaxf(m, Hf[(size_t)i * HC + c]);
    part[(size_t)blockIdx.x * HC + c] = m;
}

__global__ __launch_bounds__(256) void pool2_kernel(const float* __restrict__ part,
        float* __restrict__ out) {
    int b = blockIdx.x;
    int c = threadIdx.x;
    float m = -INFINITY;
#pragma unroll
    for (int sp = 0; sp < PSPL; ++sp)
        m = fmaxf(m, part[(size_t)(b * PSPL + sp) * HC + c]);
    out[b * HC + c] = m;
}

// ---------------- launcher ----------------

extern "C" void kernel_launch(void* const* d_in, const int* in_sizes, int n_in,
                              void* d_out, int out_size, void* d_ws, size_t ws_size,
                              hipStream_t stream) {
    const float* x     = (const float*)d_in[0];
    const int*   ei    = (const int*)d_in[1];
    const int*   batch = (const int*)d_in[2];
    const float* W1  = (const float*)d_in[3];
    const float* as1 = (const float*)d_in[4];
    const float* ad1 = (const float*)d_in[5];
    const float* b1  = (const float*)d_in[6];
    const float* W2  = (const float*)d_in[7];
    const float* as2 = (const float*)d_in[8];
    const float* ad2 = (const float*)d_in[9];
    const float* b2  = (const float*)d_in[10];
    const float* W3  = (const float*)d_in[11];
    const float* as3 = (const float*)d_in[12];
    const float* ad3 = (const float*)d_in[13];
    const float* b3  = (const float*)d_in[14];
    float* out = (float*)d_out;

    // ---- workspace layout ----
    __half* Hh  = (__half*)d_ws;                      // NN*HC f16 (layer out)
    // bufB (layer-3 fp32 out) overlays Hh + pad region (2x f16 = 1x f32 size)
    float* bufB = (float*)Hh;                         // NN*HC f32
    __half* XHh = Hh + 2 * (size_t)NN * HC;           // NN*HC f16 (xh, gathered)
    _Float16* WtS1 = (_Float16*)(XHh + (size_t)NN * HC); // 16*256*8
    _Float16* WtS2 = WtS1 + 16 * 256 * 8;             // 32*256*8
    _Float16* WtS3 = WtS2 + 32 * 256 * 8;             // 32*256*8
    float*  aS  = (float*)(WtS3 + 32 * 256 * 8);      // NN*NH
    float*  aD  = aS + NN * NH;                       // NN*NH
    float*  ppart = aD + NN * NH;                     // NB*PSPL*HC
    int* cnt    = (int*)(ppart + (size_t)NB * PSPL * HC); // NN
    int* rowptr = cnt + NN;                           // NN+1
    int* cursor = rowptr + (NN + 1);                  // NN
    int* colsrc = cursor + NN;                        // NT
    int* bstart = colsrc + NT;                        // NB+1
    int* part   = bstart + (NB + 1);                  // SCAN_B
    int* boff   = part + SCAN_B;                      // 256

    // CSR of (edges + self loops) keyed by dst, built fresh every call
    init_kernel<<<SCAN_B, 256, 0, stream>>>(batch, cnt, bstart);
    hist_kernel<<<(NT + 255) / 256, 256, 0, stream>>>(ei, cnt);
    part_kernel<<<SCAN_B, 256, 0, stream>>>(cnt, part);
    offs_kernel<<<1, 256, 0, stream>>>(part, boff);
    write_scan_kernel<<<SCAN_B, 256, 0, stream>>>(cnt, boff, rowptr, cursor);
    scatter_kernel<<<(NT + 255) / 256, 256, 0, stream>>>(ei, cursor, colsrc);
    wprep_all_kernel<<<80, 256, 0, stream>>>(W1, W2, W3, WtS1, WtS2, WtS3);

    const int gemm_grid = 2 * ((NN + 63) / 64);       // 1564 (col-split)
    const int node_grid = NN / 4;                     // 12500, exact

    // layer 1 (K=128, fp32 input, ReLU)
    mfma_gemm_kernel<FIN, true><<<gemm_grid, 256, 0, stream>>>(
        nullptr, x, WtS1, XHh, as1, ad1, aS, aD);
    aggregate_kernel<1, 1><<<node_grid, 256, 0, stream>>>(rowptr, colsrc, aS, aD, XHh, b1,
                                                          nullptr, Hh);

    // layer 2 (K=256, ReLU)
    mfma_gemm_kernel<HC, false><<<gemm_grid, 256, 0, stream>>>(
        (_Float16*)Hh, nullptr, WtS2, XHh, as2, ad2, aS, aD);
    aggregate_kernel<1, 1><<<node_grid, 256, 0, stream>>>(rowptr, colsrc, aS, aD, XHh, b2,
                                                          nullptr, Hh);

    // layer 3 (K=256, no ReLU, fp32 output for pooling)
    mfma_gemm_kernel<HC, false><<<gemm_grid, 256, 0, stream>>>(
        (_Float16*)Hh, nullptr, WtS3, XHh, as3, ad3, aS, aD);
    aggregate_kernel<0, 0><<<node_grid, 256, 0, stream>>>(rowptr, colsrc, aS, aD, XHh, b3,
                                                          bufB, nullptr);

    // global max pool over batch segments (two-stage)
    pool1_kernel<<<NB * PSPL, 256, 0, stream>>>(bufB, bstart, ppart);
    pool2_kernel<<<NB, 256, 0, stream>>>(ppart, out);
}

// Round 17
// 396.730 us; speedup vs baseline: 1.0271x; 1.0271x over previous
//
#include <hip/hip_runtime.h>
#include <hip/hip_fp16.h>
#include <math.h>

#define NN 50000          // nodes
#define NE 800000         // edges (without self loops)
#define NT 850000         // edges + self loops
#define NB 256            // batch graphs
#define FIN 128           // input feature dim
#define HC 256            // H*C
#define NH 4              // heads
#define CD 64             // channels per head
#define NEG 0.2f
#define SCAN_B 196        // ceil(NN/256)
#define PSPL 8            // pool split factor

typedef _Float16 half8 __attribute__((ext_vector_type(8)));
typedef float f32x4 __attribute__((ext_vector_type(4)));

__device__ __forceinline__ void gld16(const void* g, void* l) {
    __builtin_amdgcn_global_load_lds(
        (const __attribute__((address_space(1))) void*)g,
        (__attribute__((address_space(3))) void*)l, 16, 0, 0);
}

// ---------------- init: zero cnt, batch bounds (no cross-block comm) ----------------

__global__ __launch_bounds__(256) void init_kernel(const int* __restrict__ batch,
        int* __restrict__ cnt, int* __restrict__ bstart) {
    int i = blockIdx.x * 256 + threadIdx.x;
    if (i >= NN) return;
    cnt[i] = 0;
    int b = batch[i];
    if (i == 0) {
        for (int bb = 0; bb <= b; ++bb) bstart[bb] = 0;
    } else {
        int pb = batch[i - 1];
        if (pb != b) for (int bb = pb + 1; bb <= b; ++bb) bstart[bb] = i;
    }
    if (i == NN - 1) {
        for (int bb = b + 1; bb <= NB; ++bb) bstart[bb] = NN;
    }
}

__global__ void hist_kernel(const int* __restrict__ ei, int* __restrict__ cnt) {
    int e = blockIdx.x * blockDim.x + threadIdx.x;
    if (e < NE) {
        atomicAdd(&cnt[ei[NE + e]], 1);         // dst row of edge_index
    } else if (e < NT) {
        atomicAdd(&cnt[e - NE], 1);             // self loop
    }
}

__global__ __launch_bounds__(256) void part_kernel(const int* __restrict__ cnt,
                                                   int* __restrict__ part) {
    __shared__ int red[4];
    int i = blockIdx.x * 256 + threadIdx.x;
    int v = (i < NN) ? cnt[i] : 0;
#pragma unroll
    for (int off = 32; off > 0; off >>= 1) v += __shfl_down(v, off);
    if ((threadIdx.x & 63) == 0) red[threadIdx.x >> 6] = v;
    __syncthreads();
    if (threadIdx.x == 0) part[blockIdx.x] = red[0] + red[1] + red[2] + red[3];
}

__global__ __launch_bounds__(256) void offs_kernel(const int* __restrict__ part,
                                                   int* __restrict__ boff) {
    __shared__ int sh[256];
    int t = threadIdx.x;
    sh[t] = (t < SCAN_B) ? part[t] : 0;
    __syncthreads();
    for (int off = 1; off < 256; off <<= 1) {
        int add = (t >= off) ? sh[t - off] : 0;
        __syncthreads();
        sh[t] += add;
        __syncthreads();
    }
    boff[t] = (t == 0) ? 0 : sh[t - 1];   // exclusive block offsets
}

__global__ __launch_bounds__(256) void write_scan_kernel(const int* __restrict__ cnt,
        const int* __restrict__ boff, int* __restrict__ rowptr, int* __restrict__ cursor) {
    __shared__ int sh[256];
    int t = threadIdx.x;
    int i = blockIdx.x * 256 + t;
    int v = (i < NN) ? cnt[i] : 0;
    sh[t] = v;
    __syncthreads();
    for (int off = 1; off < 256; off <<= 1) {
        int add = (t >= off) ? sh[t - off] : 0;
        __syncthreads();
        sh[t] += add;
        __syncthreads();
    }
    int run = boff[blockIdx.x] + sh[t] - v;   // exclusive prefix
    if (i < NN) { rowptr[i] = run; cursor[i] = run; }
    if (i == NN - 1) rowptr[NN] = run + v;
}

__global__ void scatter_kernel(const int* __restrict__ ei, int* __restrict__ cursor,
                               int* __restrict__ colsrc) {
    int e = blockIdx.x * blockDim.x + threadIdx.x;
    int s, d;
    if (e < NE)      { s = ei[e]; d = ei[NE + e]; }
    else if (e < NT) { s = e - NE; d = s; }
    else return;
    int pos = atomicAdd(&cursor[d], 1);
    colsrc[pos] = s;
}

// ---------------- W prep: all 3 layers' hi-images in ONE dispatch ----------------
//   WtS[(kchunk*256 + col)*8 + e] = fp16(W[kchunk*8 + e][col])
// blocks 0..15 -> W1 (K=128), 16..47 -> W2 (K=256), 48..79 -> W3 (K=256)

__global__ __launch_bounds__(256) void wprep_all_kernel(
        const float* __restrict__ W1, const float* __restrict__ W2,
        const float* __restrict__ W3,
        _Float16* __restrict__ WtS1, _Float16* __restrict__ WtS2,
        _Float16* __restrict__ WtS3) {
    __shared__ float sm[8][257];
    const int t = threadIdx.x;
    int b = blockIdx.x;
    const float* W;
    _Float16* O;
    int lb;
    if (b < 16)      { W = W1; O = WtS1; lb = b; }
    else if (b < 48) { W = W2; O = WtS2; lb = b - 16; }
    else             { W = W3; O = WtS3; lb = b - 48; }
    const int kb = lb * 8;
#pragma unroll
    for (int i = 0; i < 8; ++i) {
        int idx = i * 256 + t;
        sm[idx >> 8][idx & 255] = W[(size_t)(kb + (idx >> 8)) * HC + (idx & 255)];
    }
    __syncthreads();
    half8 o;
#pragma unroll
    for (int r = 0; r < 8; ++r) o[r] = (_Float16)sm[r][t];
    *reinterpret_cast<half8*>(&O[((size_t)lb * 256 + t) * 8]) = o;
}

// ---- MFMA GEMM: 64(M)x128(N) tile, BK=32, 4-buffer DEPTH-3 counted-vmcnt ----
// SINGLE-PASS hi-only: C = fp16(A) @ fp16(W) with fp32 accum (verified
// absmax 4.9e-4 — error budget dominated by fp16 h storage).
// 48 KB LDS -> 3 blocks/CU. Per step:
//   loadA(s+3)->reg, issueB(s+3); MFMA(s); ds_write A(s+1);
//   vmcnt(6|8) + lgkmcnt(0); s_barrier   (2 newest batches in flight, T4)
// grid = 2 * ceil(NN/64): blockIdx.x&1 selects the 128-col half.
// F32IN: layer-1 A read from fp32 x, converted at ds_write.
// Epilogue fuses alpha: each (col-half, wave) owns ONE head's 64 channels.

template<int K, bool F32IN>
__global__ __launch_bounds__(256) void mfma_gemm_kernel(
        const _Float16* __restrict__ Xh, const float* __restrict__ Xf,
        const _Float16* __restrict__ WtS, __half* __restrict__ XHo,
        const float* __restrict__ as_g, const float* __restrict__ ad_g,
        float* __restrict__ aS, float* __restrict__ aD) {
    constexpr int NSTEP = K / 32;            // 4 (K=128) / 8 (K=256)
    __shared__ __align__(16) _Float16 As[4][64 * 32];    // 4 x 4 KB
    __shared__ __align__(16) _Float16 Bs[4][32 * 128];   // 4 x 8 KB (48 KB total)
    const int t = threadIdx.x;
    const int lane = t & 63;
    const int wid = t >> 6;                  // 0..3
    const int wm = wid & 1, wn = wid >> 1;   // 2 row-groups x 2 col-groups(64)
    const int cbb = blockIdx.x & 1;          // column half (0/1)
    const int r0 = (blockIdx.x >> 1) * 64;
    const int cb0 = cbb * 128;
    const int l15 = lane & 15;
    const int kcl = lane >> 4;               // 0..3
    const int srowA = t >> 2;                // 0..63
    const int skcA  = t & 3;                 // 0..3
    const int arow = min(r0 + srowA, NN - 1);

    f32x4 acc[2][4];
#pragma unroll
    for (int i = 0; i < 2; ++i)
#pragma unroll
        for (int j = 0; j < 4; ++j) acc[i][j] = (f32x4)0.f;

    float4 rA[3][2];                         // reg slots, batch % 3

    auto loadA = [&](int s, float4& v0, float4& v1) {
        const int cbase = s * 32;
        if constexpr (F32IN) {
            const float* p = Xf + (size_t)arow * K + cbase + skcA * 8;
            v0 = *reinterpret_cast<const float4*>(p);
            v1 = *reinterpret_cast<const float4*>(p + 4);
        } else {
            v0 = *reinterpret_cast<const float4*>(Xh + (size_t)arow * K + cbase + skcA * 8);
        }
    };
    auto writeA = [&](int buf, float4 v0, float4 v1) {
        _Float16* d = &As[buf][(skcA * 64 + (srowA ^ skcA)) * 8];
        if constexpr (F32IN) {
            float f[8];
            *reinterpret_cast<float4*>(f) = v0;
            *reinterpret_cast<float4*>(f + 4) = v1;
            half8 h;
#pragma unroll
            for (int e = 0; e < 8; ++e) h[e] = (_Float16)f[e];
            *reinterpret_cast<half8*>(d) = h;
        } else {
            *reinterpret_cast<float4*>(d) = v0;
        }
    };
    auto issueB = [&](int s, int buf) {
        const int kbase = s * 4;
#pragma unroll
        for (int r2 = 0; r2 < 2; ++r2) {
            int kc = r2 * 2 + (t >> 7);      // 0..3, wave-uniform
            int col = t & 127;
            gld16(WtS + ((size_t)(kbase + kc) * 256 + cb0 + col) * 8,
                  &Bs[buf][(kc * 128 + col) * 8]);
        }
    };
    auto mfma_step = [&](int buf) {
        half8 a0 = *reinterpret_cast<const half8*>(
            &As[buf][(kcl * 64 + ((wm * 32      + l15) ^ kcl)) * 8]);
        half8 a1 = *reinterpret_cast<const half8*>(
            &As[buf][(kcl * 64 + ((wm * 32 + 16 + l15) ^ kcl)) * 8]);
        const _Float16* bp = &Bs[buf][(kcl * 128 + wn * 64 + l15) * 8];
        __builtin_amdgcn_s_setprio(1);
#pragma unroll
        for (int nf = 0; nf < 4; ++nf) {
            half8 b = *reinterpret_cast<const half8*>(bp + nf * 16 * 8);
            acc[0][nf] = __builtin_amdgcn_mfma_f32_16x16x32_f16(a0, b, acc[0][nf], 0, 0, 0);
            acc[1][nf] = __builtin_amdgcn_mfma_f32_16x16x32_f16(a1, b, acc[1][nf], 0, 0, 0);
        }
        __builtin_amdgcn_s_setprio(0);
    };
    auto wait_steady = [&]() {
        if constexpr (F32IN) asm volatile("s_waitcnt vmcnt(8) lgkmcnt(0)" ::: "memory");
        else                 asm volatile("s_waitcnt vmcnt(6) lgkmcnt(0)" ::: "memory");
        __builtin_amdgcn_s_barrier();
        __builtin_amdgcn_sched_barrier(0);
    };

    // prologue: 3 batches in flight, A0 written, batch 0 complete
    loadA(0, rA[0][0], rA[0][1]); issueB(0, 0);
    loadA(1, rA[1][0], rA[1][1]); issueB(1, 1);
    loadA(2, rA[2][0], rA[2][1]); issueB(2, 2);
    writeA(0, rA[0][0], rA[0][1]);
    wait_steady();

#pragma unroll
    for (int s = 0; s < NSTEP - 3; ++s) {
        loadA(s + 3, rA[(s + 3) % 3][0], rA[(s + 3) % 3][1]);
        issueB(s + 3, (s + 3) & 3);
        mfma_step(s & 3);
        writeA((s + 1) & 3, rA[(s + 1) % 3][0], rA[(s + 1) % 3][1]);
        wait_steady();
    }
    // tail: s = NSTEP-3, NSTEP-2, NSTEP-1
    mfma_step((NSTEP - 3) & 3);
    writeA((NSTEP - 2) & 3, rA[(NSTEP - 2) % 3][0], rA[(NSTEP - 2) % 3][1]);
    if constexpr (F32IN) asm volatile("s_waitcnt vmcnt(4) lgkmcnt(0)" ::: "memory");
    else                 asm volatile("s_waitcnt vmcnt(3) lgkmcnt(0)" ::: "memory");
    __builtin_amdgcn_s_barrier();
    __builtin_amdgcn_sched_barrier(0);
    mfma_step((NSTEP - 2) & 3);
    writeA((NSTEP - 1) & 3, rA[(NSTEP - 1) % 3][0], rA[(NSTEP - 1) % 3][1]);
    asm volatile("s_waitcnt vmcnt(0) lgkmcnt(0)" ::: "memory");
    __builtin_amdgcn_s_barrier();
    __builtin_amdgcn_sched_barrier(0);
    mfma_step((NSTEP - 1) & 3);

    // ---------------- epilogue: XH stores + fused alpha (one head/wave) ------
    const int rb = r0 + wm * 32 + (lane >> 4) * 4;
    const int cbg = cb0 + wn * 64 + l15;     // global column of frag lane
    const int head = cbb * 2 + wn;
    float asv[4], adv[4];
#pragma unroll
    for (int nf = 0; nf < 4; ++nf) {
        asv[nf] = as_g[cbg + nf * 16];
        adv[nf] = ad_g[cbg + nf * 16];
    }
#pragma unroll
    for (int mf = 0; mf < 2; ++mf)
#pragma unroll
        for (int r = 0; r < 4; ++r) {
            int row = rb + mf * 16 + r;
            float s0 = 0.f, d0 = 0.f;
#pragma unroll
            for (int nf = 0; nf < 4; ++nf) {
                float a = acc[mf][nf][r];
                s0 += a * asv[nf];
                d0 += a * adv[nf];
            }
#pragma unroll
            for (int off = 1; off < 16; off <<= 1) {
                s0 += __shfl_xor(s0, off);
                d0 += __shfl_xor(d0, off);
            }
            if (row < NN) {
                if (l15 == 0) {
                    aS[row * 4 + head] = s0;
                    aD[row * 4 + head] = d0;
                }
#pragma unroll
                for (int nf = 0; nf < 4; ++nf)
                    XHo[(size_t)row * HC + cbg + nf * 16] = __float2half(acc[mf][nf][r]);
            }
        }
}

// ---- aggregation with fused edge-weights: one wave per node ----
// Round-14 two-load form (proven fastest) + bijective XCD-chunk swizzle:
// batch-sorted nodes mean consecutive blocks share a graph's neighbor set;
// giving each XCD a CONTIGUOUS node chunk fits that graph's xh slice
// (~25MB/8 ~ 3MB) in its private 4MB L2. m204 formula (12500 % 8 != 0).

#define LEAKY(v) ((v) > 0.f ? (v) : NEG * (v))

template<int RELU, int SPLIT>
__global__ __launch_bounds__(256) void aggregate_kernel(
        const int* __restrict__ rowptr, const int* __restrict__ colsrc,
        const float* __restrict__ aS, const float* __restrict__ aD,
        const __half* __restrict__ XH,
        const float* __restrict__ bias, float* __restrict__ OUT,
        __half* __restrict__ OUTh) {
    __shared__ float4 wbuf[4][64];
    __shared__ int    ibuf[4][64];
    const int wslot = threadIdx.x >> 6;
    // bijective XCD-chunk swizzle of the block id (nwg = 12500, q=1562, r=4)
    const int nwg = NN / 4;
    const int q = nwg >> 3, r = nwg & 7;
    int orig = blockIdx.x;
    int xcd = orig & 7, k = orig >> 3;
    int blk = (xcd < r ? xcd * (q + 1) : r * (q + 1) + (xcd - r) * q) + k;
    int n = blk * 4 + wslot;
    int lane = threadIdx.x & 63;
    bool lo = lane < 32;
    const __half2* xbase = reinterpret_cast<const __half2*>(XH);
    float4 adv = *reinterpret_cast<const float4*>(aD + n * 4);
    float zl = 0.f, zh = 0.f;
    float al0 = 0.f, al1 = 0.f, ah0 = 0.f, ah1 = 0.f;
    int jb = rowptr[n], je = rowptr[n + 1];   // deg >= 1 (self loop)
    for (int c0 = jb; c0 < je; c0 += 64) {
        int cnt = min(64, je - c0);
        {
            int e = min(c0 + lane, je - 1);
            int s = colsrc[e];
            float4 sv = *reinterpret_cast<const float4*>(aS + s * 4);
            float4 w;
            w.x = __expf(LEAKY(sv.x + adv.x));
            w.y = __expf(LEAKY(sv.y + adv.y));
            w.z = __expf(LEAKY(sv.z + adv.z));
            w.w = __expf(LEAKY(sv.w + adv.w));
            wbuf[wslot][lane] = w;
            ibuf[wslot][lane] = s;
        }
        int u = 0;
        for (; u + 8 <= cnt; u += 8) {
            int sidx[8];
            float4 w[8];
#pragma unroll
            for (int k2 = 0; k2 < 8; ++k2) { sidx[k2] = ibuf[wslot][u + k2]; w[k2] = wbuf[wslot][u + k2]; }
            __half2 p[8], qv[8];
#pragma unroll
            for (int k2 = 0; k2 < 8; ++k2) {
                const __half2* xp = xbase + (size_t)sidx[k2] * (HC / 2) + lane;
                p[k2] = xp[0];
                qv[k2] = xp[64];
            }
#pragma unroll
            for (int k2 = 0; k2 < 8; ++k2) {
                float wl = lo ? w[k2].x : w[k2].y, wh = lo ? w[k2].z : w[k2].w;
                float2 f = __half22float2(p[k2]);
                al0 += wl * f.x; al1 += wl * f.y;
                f = __half22float2(qv[k2]);
                ah0 += wh * f.x; ah1 += wh * f.y;
                zl += wl; zh += wh;
            }
        }
        for (; u < cnt; ++u) {
            int s0 = ibuf[wslot][u];
            float4 w0 = wbuf[wslot][u];
            const __half2* xp = xbase + (size_t)s0 * (HC / 2) + lane;
            __half2 p0 = xp[0], q0 = xp[64];
            float w0l = lo ? w0.x : w0.y, w0h = lo ? w0.z : w0.w;
            float2 f = __half22float2(p0);
            al0 += w0l * f.x; al1 += w0l * f.y;
            f = __half22float2(q0);
            ah0 += w0h * f.x; ah1 += w0h * f.y;
            zl += w0l; zh += w0h;
        }
    }
    float izl = 1.f / (zl + 1e-16f), izh = 1.f / (zh + 1e-16f);
    float2 bl = reinterpret_cast<const float2*>(bias)[lane];
    float2 bh = reinterpret_cast<const float2*>(bias + 128)[lane];
    float o0 = al0 * izl + bl.x;
    float o1 = al1 * izl + bl.y;
    float o2 = ah0 * izh + bh.x;
    float o3 = ah1 * izh + bh.y;
    if (RELU) {
        o0 = fmaxf(o0, 0.f); o1 = fmaxf(o1, 0.f);
        o2 = fmaxf(o2, 0.f); o3 = fmaxf(o3, 0.f);
    }
    if (SPLIT) {
        __half2* ph = reinterpret_cast<__half2*>(OUTh + (size_t)n * HC) + lane;
        ph[0]  = __half2(__float2half(o0), __float2half(o1));
        ph[64] = __half2(__float2half(o2), __float2half(o3));
    } else {
        float2* op = reinterpret_cast<float2*>(OUT + (size_t)n * HC) + lane;
        op[0]  = make_float2(o0, o1);
        op[64] = make_float2(o2, o3);
    }
}

// ---------------- global max pool (two-stage, deterministic) ----------------

__global__ __launch_bounds__(256) void pool1_kernel(const float* __restrict__ Hf,
        const int* __restrict__ bstart, float* __restrict__ part) {
    int b = blockIdx.x / PSPL, sp = blockIdx.x % PSPL;
    int c = threadIdx.x;
    int i0 = bstart[b], i1 = bstart[b + 1];
    float m = -INFINITY;
    for (int i = i0 + sp; i < i1; i += PSPL) m = fmaxf(m, Hf[(size_t)i * HC + c]);
    part[(size_t)blockIdx.x * HC + c] = m;
}

__global__ __launch_bounds__(256) void pool2_kernel(const float* __restrict__ part,
        float* __restrict__ out) {
    int b = blockIdx.x;
    int c = threadIdx.x;
    float m = -INFINITY;
#pragma unroll
    for (int sp = 0; sp < PSPL; ++sp)
        m = fmaxf(m, part[(size_t)(b * PSPL + sp) * HC + c]);
    out[b * HC + c] = m;
}

// ---------------- launcher ----------------

extern "C" void kernel_launch(void* const* d_in, const int* in_sizes, int n_in,
                              void* d_out, int out_size, void* d_ws, size_t ws_size,
                              hipStream_t stream) {
    const float* x     = (const float*)d_in[0];
    const int*   ei    = (const int*)d_in[1];
    const int*   batch = (const int*)d_in[2];
    const float* W1  = (const float*)d_in[3];
    const float* as1 = (const float*)d_in[4];
    const float* ad1 = (const float*)d_in[5];
    const float* b1  = (const float*)d_in[6];
    const float* W2  = (const float*)d_in[7];
    const float* as2 = (const float*)d_in[8];
    const float* ad2 = (const float*)d_in[9];
    const float* b2  = (const float*)d_in[10];
    const float* W3  = (const float*)d_in[11];
    const float* as3 = (const float*)d_in[12];
    const float* ad3 = (const float*)d_in[13];
    const float* b3  = (const float*)d_in[14];
    float* out = (float*)d_out;

    // ---- workspace layout ----
    __half* Hh  = (__half*)d_ws;                      // NN*HC f16 (layer out)
    // bufB (layer-3 fp32 out) overlays Hh + pad region (2x f16 = 1x f32 size)
    float* bufB = (float*)Hh;                         // NN*HC f32
    __half* XHh = Hh + 2 * (size_t)NN * HC;           // NN*HC f16 (xh, gathered)
    _Float16* WtS1 = (_Float16*)(XHh + (size_t)NN * HC); // 16*256*8
    _Float16* WtS2 = WtS1 + 16 * 256 * 8;             // 32*256*8
    _Float16* WtS3 = WtS2 + 32 * 256 * 8;             // 32*256*8
    float*  aS  = (float*)(WtS3 + 32 * 256 * 8);      // NN*NH
    float*  aD  = aS + NN * NH;                       // NN*NH
    float*  ppart = aD + NN * NH;                     // NB*PSPL*HC
    int* cnt    = (int*)(ppart + (size_t)NB * PSPL * HC); // NN
    int* rowptr = cnt + NN;                           // NN+1
    int* cursor = rowptr + (NN + 1);                  // NN
    int* colsrc = cursor + NN;                        // NT
    int* bstart = colsrc + NT;                        // NB+1
    int* part   = bstart + (NB + 1);                  // SCAN_B
    int* boff   = part + SCAN_B;                      // 256

    // CSR of (edges + self loops) keyed by dst, built fresh every call
    init_kernel<<<SCAN_B, 256, 0, stream>>>(batch, cnt, bstart);
    hist_kernel<<<(NT + 255) / 256, 256, 0, stream>>>(ei, cnt);
    part_kernel<<<SCAN_B, 256, 0, stream>>>(cnt, part);
    offs_kernel<<<1, 256, 0, stream>>>(part, boff);
    write_scan_kernel<<<SCAN_B, 256, 0, stream>>>(cnt, boff, rowptr, cursor);
    scatter_kernel<<<(NT + 255) / 256, 256, 0, stream>>>(ei, cursor, colsrc);
    wprep_all_kernel<<<80, 256, 0, stream>>>(W1, W2, W3, WtS1, WtS2, WtS3);

    const int gemm_grid = 2 * ((NN + 63) / 64);       // 1564 (col-split)
    const int node_grid = NN / 4;                     // 12500, exact

    // layer 1 (K=128, fp32 input, ReLU)
    mfma_gemm_kernel<FIN, true><<<gemm_grid, 256, 0, stream>>>(
        nullptr, x, WtS1, XHh, as1, ad1, aS, aD);
    aggregate_kernel<1, 1><<<node_grid, 256, 0, stream>>>(rowptr, colsrc, aS, aD, XHh, b1,
                                                          nullptr, Hh);

    // layer 2 (K=256, ReLU)
    mfma_gemm_kernel<HC, false><<<gemm_grid, 256, 0, stream>>>(
        (_Float16*)Hh, nullptr, WtS2, XHh, as2, ad2, aS, aD);
    aggregate_kernel<1, 1><<<node_grid, 256, 0, stream>>>(rowptr, colsrc, aS, aD, XHh, b2,
                                                          nullptr, Hh);

    // layer 3 (K=256, no ReLU, fp32 output for pooling)
    mfma_gemm_kernel<HC, false><<<gemm_grid, 256, 0, stream>>>(
        (_Float16*)Hh, nullptr, WtS3, XHh, as3, ad3, aS, aD);
    aggregate_kernel<0, 0><<<node_grid, 256, 0, stream>>>(rowptr, colsrc, aS, aD, XHh, b3,
                                                          bufB, nullptr);

    // global max pool over batch segments (two-stage)
    pool1_kernel<<<NB * PSPL, 256, 0, stream>>>(bufB, bstart, ppart);
    pool2_kernel<<<NB, 256, 0, stream>>>(ppart, out);
}